// Round 11
// baseline (129.759 us; speedup 1.0000x reference)
//
#include <hip/hip_runtime.h>

typedef __fp16 f16;
typedef f16  h8 __attribute__((ext_vector_type(8)));
typedef float f4 __attribute__((ext_vector_type(4)));
typedef unsigned u32t;

#define NBLOCKS 768              // 256 CUs x 3 blocks/CU co-resident (VGPR-bound)
#define WPB 4
#define NWAVES (NBLOCKS * WPB)   // 3072
#define NBAT (262144 / 16)       // 16384 batches of 16 samples
#define K2L 2.8853900817779268f  // 2*log2(e):  e^{2a} = 2^{K2L*a}

union H8u { h8 v; u32t u[4]; };
union U4h { uint4 u; h8 v; };

__device__ __forceinline__ u32t pk2(float a, float b) {
    return __builtin_bit_cast(u32t, __builtin_amdgcn_cvt_pkrtz(a, b));
}

// h = tanh(a), g = sech^2(a) given t = K2L*a (E = 2^t = e^{2a}); NaN-free at sat.
__device__ __forceinline__ void tanh_sech2_t(float t, float& h, float& g) {
    float E = __builtin_amdgcn_exp2f(t);
    float inv = __builtin_amdgcn_rcpf(E + 1.f);
    float u = inv + inv;
    h = 1.f - u;
    g = u * (2.f - u);
}

// R11 = R10 (measured clean: FETCH 2.26MB) with the LDS exchange deleted:
//  - L1 emits B2-fragments directly in unit-order 32kk+8q+2p+o (R5-validated);
//  - L2 -> L3 via pi3 same-lane register repack (R5-validated math);
//  - A2 fragments stay in registers; A3 lives in an 8KB LDS frag buffer read
//    per-mt in L3 (frees 32 persistent regs -> peak ~157 < the ~170 cap of
//    __launch_bounds__(256,3); R5's all-register version spilled at ~185).
// Register cliff warning (R5-R9): adding ANY persistent live state here will
// spill to scratch -- watch FETCH_SIZE, must stay ~2.3MB.
__global__ __launch_bounds__(256, 3) void pinn_mfma_kernel(
    const float* __restrict__ x_r, const float* __restrict__ sigma_r,
    const float* __restrict__ W1, const float* __restrict__ b1,
    const float* __restrict__ W2, const float* __restrict__ b2,
    const float* __restrict__ W3, const float* __restrict__ b3,
    const float* __restrict__ W4, float* __restrict__ out)
{
    __shared__ uint4 F3[8][64];             // A3 frags under pi3, 8 KB
    __shared__ f4 Wk[64];                   // (K*w1x, K*w1y, K*w1z, K*b1)
    __shared__ f4 Wd[64];                   // (w1x, w1y, w1z, -2*Q1)
    __shared__ f4 BbK2[16], BbK3[16], W4v[16];

    const int tid = threadIdx.x, lane = tid & 63, wv = tid >> 6;
    const int sb = lane & 15;   // sample slot (B/C col)
    const int q  = lane >> 4;   // lane quarter (C row group / B k-chunk)

    if (tid < 64) {
        float wx = W1[tid], wy = W1[64 + tid], wz = W1[128 + tid];
        f4 a; a[0] = K2L * wx; a[1] = K2L * wy; a[2] = K2L * wz; a[3] = K2L * b1[tid];
        Wk[tid] = a;
        f4 d; d[0] = wx; d[1] = wy; d[2] = wz; d[3] = -2.f * (wx*wx + wy*wy + wz*wz);
        Wd[tid] = d;
        ((float*)BbK2)[tid] = K2L * b2[tid];
        ((float*)BbK3)[tid] = K2L * b3[tid];
        ((float*)W4v)[tid]  = W4[tid];
    }
    // Fill F3 (pi3 rows: 32kk + 16*(p>>1) + 4*qq + 2*(p&1) + o), 2 slots/thread.
#pragma unroll
    for (int i = 0; i < 2; ++i) {
        const int slot = i * 256 + tid;      // 0..511
        const int fg = slot >> 6, ln = slot & 63;
        const int mt = fg >> 1, kk = fg & 1;
        const int qq = ln >> 4, col = 16 * mt + (ln & 15);
        const int rb = (32 * kk + 4 * qq) * 64 + col;
        F3[fg][ln] = make_uint4(
            pk2(W3[rb],        W3[rb + 64]),
            pk2(W3[rb + 128],  W3[rb + 192]),
            pk2(W3[rb + 1024], W3[rb + 1088]),
            pk2(W3[rb + 1152], W3[rb + 1216]));
    }
    __syncthreads();   // the only barrier

    // ---- A2 fragments in registers (identity k-map): A[m][k] = W2[k][m] ----
    h8 A2f[4][2];
#pragma unroll
    for (int mt = 0; mt < 4; ++mt)
#pragma unroll
    for (int kk = 0; kk < 2; ++kk) {
        H8u t2;
#pragma unroll
        for (int p = 0; p < 4; ++p) {
            const int r0 = (32 * kk + 8 * q + 2 * p) * 64 + 16 * mt + sb;
            t2.u[p] = pk2(W2[r0], W2[r0 + 64]);
        }
        A2f[mt][kk] = t2.v;
    }

    const int wave_global = blockIdx.x * WPB + wv;

    // prefetch first batch
    int b = wave_global;
    long sp0 = (long)b * 16 + sb;
    float nx0 = x_r[sp0 * 3], nx1 = x_r[sp0 * 3 + 1], nx2 = x_r[sp0 * 3 + 2],
          nsg = sigma_r[sp0];

#pragma unroll 1
    for (; b < NBAT; b += NWAVES) {
        const float x0 = nx0, x1 = nx1, x2 = nx2, sg = nsg;
        int bn = b + NWAVES;
        if (bn >= NBAT) bn = wave_global;      // dummy re-prefetch on last iter (benign)
        const long sn = (long)bn * 16 + sb;
        nx0 = x_r[sn * 3]; nx1 = x_r[sn * 3 + 1]; nx2 = x_r[sn * 3 + 2];
        nsg = sigma_r[sn];

        // ---- layer 1 straight into B2 fragments (unit = 32kk+8q+2p+o) ----
        H8u Bh[2], Bx[2], By[2], Bz[2], Bs[2];
#pragma unroll
        for (int kk = 0; kk < 2; ++kk)
#pragma unroll
        for (int p = 0; p < 4; ++p) {
            float hv[2], xv[2], yv[2], zv[2], sv[2];
#pragma unroll
            for (int o = 0; o < 2; ++o) {
                const int u = 32 * kk + 8 * q + 2 * p + o;
                const f4 wk = Wk[u], wd = Wd[u];
                const float tt = fmaf(wk[0], x0, fmaf(wk[1], x1, fmaf(wk[2], x2, wk[3])));
                float h, g; tanh_sech2_t(tt, h, g);
                hv[o] = h; xv[o] = g * wd[0]; yv[o] = g * wd[1]; zv[o] = g * wd[2];
                sv[o] = (h * g) * wd[3];
            }
            Bh[kk].u[p] = pk2(hv[0], hv[1]); Bx[kk].u[p] = pk2(xv[0], xv[1]);
            By[kk].u[p] = pk2(yv[0], yv[1]); Bz[kk].u[p] = pk2(zv[0], zv[1]);
            Bs[kk].u[p] = pk2(sv[0], sv[1]);
        }

        // ---- layer 2: per-mt MFMA -> NL -> pi3 same-lane repack into N-frags ----
        H8u Nh[2], Nx[2], Ny[2], Nz[2], Ns[2];
#pragma unroll
        for (int mt = 0; mt < 4; ++mt) {
            f4 Ch = {0.f,0.f,0.f,0.f}, Cx = {0.f,0.f,0.f,0.f}, Cy = {0.f,0.f,0.f,0.f},
               Cz = {0.f,0.f,0.f,0.f}, Cs = {0.f,0.f,0.f,0.f};
#pragma unroll
            for (int kk = 0; kk < 2; ++kk) {
                const h8 A = A2f[mt][kk];
                Ch = __builtin_amdgcn_mfma_f32_16x16x32_f16(A, Bh[kk].v, Ch, 0, 0, 0);
                Cx = __builtin_amdgcn_mfma_f32_16x16x32_f16(A, Bx[kk].v, Cx, 0, 0, 0);
                Cy = __builtin_amdgcn_mfma_f32_16x16x32_f16(A, By[kk].v, Cy, 0, 0, 0);
                Cz = __builtin_amdgcn_mfma_f32_16x16x32_f16(A, Bz[kk].v, Cz, 0, 0, 0);
                Cs = __builtin_amdgcn_mfma_f32_16x16x32_f16(A, Bs[kk].v, Cs, 0, 0, 0);
            }
            const f4 bb = BbK2[4 * mt + q];
            float oh[4], ox[4], oy[4], oz[4], os[4];
#pragma unroll
            for (int r = 0; r < 4; ++r) {
                float h, g; tanh_sech2_t(fmaf(Ch[r], K2L, bb[r]), h, g);
                const float ax = Cx[r], ay = Cy[r], az = Cz[r];
                const float qq  = fmaf(ax, ax, fmaf(ay, ay, az * az));
                const float hg2 = (h * g) * 2.f;
                oh[r] = h; ox[r] = g * ax; oy[r] = g * ay; oz[r] = g * az;
                os[r] = fmaf(g, Cs[r], -(hg2 * qq));
            }
            const int ko = mt >> 1, po = 2 * (mt & 1);
            Nh[ko].u[po] = pk2(oh[0], oh[1]); Nh[ko].u[po + 1] = pk2(oh[2], oh[3]);
            Nx[ko].u[po] = pk2(ox[0], ox[1]); Nx[ko].u[po + 1] = pk2(ox[2], ox[3]);
            Ny[ko].u[po] = pk2(oy[0], oy[1]); Ny[ko].u[po + 1] = pk2(oy[2], oy[3]);
            Nz[ko].u[po] = pk2(oz[0], oz[1]); Nz[ko].u[po + 1] = pk2(oz[2], oz[3]);
            Ns[ko].u[po] = pk2(os[0], os[1]); Ns[ko].u[po + 1] = pk2(os[2], os[3]);
        }

        // ---- layer 3: A3 frags streamed from LDS per-mt -> NL -> W4 dot ----
        float tot = 0.f;
#pragma unroll
        for (int mt = 0; mt < 4; ++mt) {
            f4 Ch = {0.f,0.f,0.f,0.f}, Cx = {0.f,0.f,0.f,0.f}, Cy = {0.f,0.f,0.f,0.f},
               Cz = {0.f,0.f,0.f,0.f}, Cs = {0.f,0.f,0.f,0.f};
#pragma unroll
            for (int kk = 0; kk < 2; ++kk) {
                U4h au; au.u = F3[2 * mt + kk][lane];
                const h8 A = au.v;
                Ch = __builtin_amdgcn_mfma_f32_16x16x32_f16(A, Nh[kk].v, Ch, 0, 0, 0);
                Cx = __builtin_amdgcn_mfma_f32_16x16x32_f16(A, Nx[kk].v, Cx, 0, 0, 0);
                Cy = __builtin_amdgcn_mfma_f32_16x16x32_f16(A, Ny[kk].v, Cy, 0, 0, 0);
                Cz = __builtin_amdgcn_mfma_f32_16x16x32_f16(A, Nz[kk].v, Cz, 0, 0, 0);
                Cs = __builtin_amdgcn_mfma_f32_16x16x32_f16(A, Ns[kk].v, Cs, 0, 0, 0);
            }
            const f4 bb = BbK3[4 * mt + q], w4 = W4v[4 * mt + q];
#pragma unroll
            for (int r = 0; r < 4; ++r) {
                float h, g; tanh_sech2_t(fmaf(Ch[r], K2L, bb[r]), h, g);
                const float ax = Cx[r], ay = Cy[r], az = Cz[r];
                const float qq  = fmaf(ax, ax, fmaf(ay, ay, az * az));
                const float hg2 = (h * g) * 2.f;
                const float sv  = fmaf(g, Cs[r], -(hg2 * qq));
                tot = fmaf(sv, w4[r], tot);
            }
        }
        tot += __shfl_xor(tot, 16);
        tot += __shfl_xor(tot, 32);
        if (lane < 16) out[(long)b * 16 + sb] = sg * tot;
    }
}

extern "C" void kernel_launch(void* const* d_in, const int* in_sizes, int n_in,
                              void* d_out, int out_size, void* d_ws, size_t ws_size,
                              hipStream_t stream) {
    const float* x_r     = (const float*)d_in[0];
    const float* sigma_r = (const float*)d_in[1];
    const float* W1      = (const float*)d_in[2];
    const float* b1      = (const float*)d_in[3];
    const float* W2      = (const float*)d_in[4];
    const float* b2      = (const float*)d_in[5];
    const float* W3      = (const float*)d_in[6];
    const float* b3      = (const float*)d_in[7];
    const float* W4      = (const float*)d_in[8];
    float* out = (float*)d_out;

    pinn_mfma_kernel<<<NBLOCKS, 256, 0, stream>>>(
        x_r, sigma_r, W1, b1, W2, b2, W3, b3, W4, out);
}

// Round 12
// 106.271 us; speedup vs baseline: 1.2210x; 1.2210x over previous
//
#include <hip/hip_runtime.h>

typedef __fp16 f16;
typedef f16  h8 __attribute__((ext_vector_type(8)));
typedef float f4 __attribute__((ext_vector_type(4)));
typedef unsigned u32t;

#define NBLOCKS 768              // 256 CUs x 3 blocks/CU co-resident
#define WPB 4
#define NWAVES (NBLOCKS * WPB)   // 3072
#define NBAT (262144 / 16)       // 16384 batches of 16 samples
#define XSTR 36                  // u32 per sample row (even, 16B-aligned rows)
#define XST  (16 * XSTR)         // u32 per state
#define K2L 2.8853900817779268f  // 2*log2(e):  e^{2a} = 2^{K2L*a}

union H8u { h8 v; u32t u[4]; };
union U4h { uint4 u; h8 v; };

__device__ __forceinline__ u32t pk2(float a, float b) {
    return __builtin_bit_cast(u32t, __builtin_amdgcn_cvt_pkrtz(a, b));
}

// h = tanh(a), g = sech^2(a) given t = K2L*a (E = 2^t = e^{2a}); NaN-free at sat.
__device__ __forceinline__ void tanh_sech2_t(float t, float& h, float& g) {
    float E = __builtin_amdgcn_exp2f(t);
    float inv = __builtin_amdgcn_rcpf(E + 1.f);
    float u = inv + inv;
    h = 1.f - u;
    g = u * (2.f - u);
}

// R12 = R10 (clean: FETCH 2.26MB, 42.6us) minus the L1->L2 exchange: layer 1
// emits B2-fragments directly in unit-order 32kk+8q+2p+o (R5/R11-validated
// numerics). Pressure-NEUTRAL: the direct B-frags are the same 40 regs R10
// filled via RDB; L1's oh[]..os[] staging disappears in trade.
// REGISTER CLIFF LAW (R5-R9,R11): any SECOND live fragment set (pi3 N-frags
// +40, or held uint2s +16) on top of A(64)+B(40)+C(20) spills to scratch
// (FETCH 2.3MB -> 270-450MB). Layer-3 B-frags MUST be re-loaded from LDS into
// the SAME registers (RDB into Bh..Bs). Watch FETCH_SIZE == ~2.3MB.
__global__ __launch_bounds__(256, 3) void pinn_mfma_kernel(
    const float* __restrict__ x_r, const float* __restrict__ sigma_r,
    const float* __restrict__ W1, const float* __restrict__ b1,
    const float* __restrict__ W2, const float* __restrict__ b2,
    const float* __restrict__ W3, const float* __restrict__ b3,
    const float* __restrict__ W4, float* __restrict__ out)
{
    __shared__ f4 Wk[64];                   // (K*w1x, K*w1y, K*w1z, K*b1)
    __shared__ f4 Wd[64];                   // (w1x, w1y, w1z, -2*Q1)
    __shared__ f4 BbK2[16], BbK3[16], W4v[16];
    __shared__ u32t xch[WPB][5 * XST];      // f16-pair exchange (L2->L3), 46 KB

    const int tid = threadIdx.x, lane = tid & 63, wv = tid >> 6;
    const int sb = lane & 15;   // sample slot (B/C col)
    const int q  = lane >> 4;   // lane quarter (C row group / B k-chunk)

    if (tid < 64) {
        float wx = W1[tid], wy = W1[64 + tid], wz = W1[128 + tid];
        f4 a; a[0] = K2L * wx; a[1] = K2L * wy; a[2] = K2L * wz; a[3] = K2L * b1[tid];
        Wk[tid] = a;
        f4 d; d[0] = wx; d[1] = wy; d[2] = wz; d[3] = -2.f * (wx*wx + wy*wy + wz*wz);
        Wd[tid] = d;
        ((float*)BbK2)[tid] = K2L * b2[tid];
        ((float*)BbK3)[tid] = K2L * b3[tid];
        ((float*)W4v)[tid]  = W4[tid];
    }
    __syncthreads();   // the only barrier

    // ---- A-fragments (validated mapping): A[m][k] = W[32kk+8q+e][16mt+sb] ----
    h8 A2f[4][2], A3f[4][2];
#pragma unroll
    for (int mt = 0; mt < 4; ++mt)
#pragma unroll
    for (int kk = 0; kk < 2; ++kk) {
        H8u t2, t3;
#pragma unroll
        for (int p = 0; p < 4; ++p) {
            const int r0 = (32 * kk + 8 * q + 2 * p) * 64 + 16 * mt + sb;
            t2.u[p] = pk2(W2[r0], W2[r0 + 64]);
            t3.u[p] = pk2(W3[r0], W3[r0 + 64]);
        }
        A2f[mt][kk] = t2.v; A3f[mt][kk] = t3.v;
    }

    u32t* xb = xch[wv];
    const int wbase = sb * XSTR + 2 * q;   // + 8*mt + st*XST   (b64 writes)
    const int rbase = sb * XSTR + 4 * q;   // + 16*kk + st*XST  (b128 reads)

    const int wave_global = blockIdx.x * WPB + wv;

#define WR5(mt) { const int wo = wbase + 8 * (mt);                                         \
    *(uint2*)&xb[0 * XST + wo] = make_uint2(pk2(oh[0], oh[1]), pk2(oh[2], oh[3]));         \
    *(uint2*)&xb[1 * XST + wo] = make_uint2(pk2(ox[0], ox[1]), pk2(ox[2], ox[3]));         \
    *(uint2*)&xb[2 * XST + wo] = make_uint2(pk2(oy[0], oy[1]), pk2(oy[2], oy[3]));         \
    *(uint2*)&xb[3 * XST + wo] = make_uint2(pk2(oz[0], oz[1]), pk2(oz[2], oz[3]));         \
    *(uint2*)&xb[4 * XST + wo] = make_uint2(pk2(os[0], os[1]), pk2(os[2], os[3])); }

#define RDB(Bf, st) { U4h u0, u1;                                                          \
    u0.u = *(const uint4*)&xb[(st) * XST + rbase];                                         \
    u1.u = *(const uint4*)&xb[(st) * XST + rbase + 16];                                    \
    Bf[0].v = u0.v; Bf[1].v = u1.v; }

#define MFMA10(Af) _Pragma("unroll")                                                       \
    for (int kk = 0; kk < 2; ++kk) {                                                       \
        Ch = __builtin_amdgcn_mfma_f32_16x16x32_f16(Af[mt][kk], Bh[kk].v, Ch, 0, 0, 0);    \
        Cx = __builtin_amdgcn_mfma_f32_16x16x32_f16(Af[mt][kk], Bx[kk].v, Cx, 0, 0, 0);    \
        Cy = __builtin_amdgcn_mfma_f32_16x16x32_f16(Af[mt][kk], By[kk].v, Cy, 0, 0, 0);    \
        Cz = __builtin_amdgcn_mfma_f32_16x16x32_f16(Af[mt][kk], Bz[kk].v, Cz, 0, 0, 0);    \
        Cs = __builtin_amdgcn_mfma_f32_16x16x32_f16(Af[mt][kk], Bs[kk].v, Cs, 0, 0, 0);    \
    }

    // prefetch first batch
    int b = wave_global;
    long sp0 = (long)b * 16 + sb;
    float nx0 = x_r[sp0 * 3], nx1 = x_r[sp0 * 3 + 1], nx2 = x_r[sp0 * 3 + 2],
          nsg = sigma_r[sp0];

#pragma unroll 1
    for (; b < NBAT; b += NWAVES) {
        const float x0 = nx0, x1 = nx1, x2 = nx2, sg = nsg;
        int bn = b + NWAVES;
        if (bn >= NBAT) bn = wave_global;      // dummy re-prefetch on last iter (benign)
        const long sn = (long)bn * 16 + sb;
        nx0 = x_r[sn * 3]; nx1 = x_r[sn * 3 + 1]; nx2 = x_r[sn * 3 + 2];
        nsg = sigma_r[sn];

        // ---- layer 1 straight into B2 fragments (unit = 32kk+8q+2p+o) ----
        H8u Bh[2], Bx[2], By[2], Bz[2], Bs[2];
#pragma unroll
        for (int kk = 0; kk < 2; ++kk)
#pragma unroll
        for (int p = 0; p < 4; ++p) {
            float hv[2], xv[2], yv[2], zv[2], sv[2];
#pragma unroll
            for (int o = 0; o < 2; ++o) {
                const int u = 32 * kk + 8 * q + 2 * p + o;
                const f4 wk = Wk[u], wd = Wd[u];
                const float tt = fmaf(wk[0], x0, fmaf(wk[1], x1, fmaf(wk[2], x2, wk[3])));
                float h, g; tanh_sech2_t(tt, h, g);
                hv[o] = h; xv[o] = g * wd[0]; yv[o] = g * wd[1]; zv[o] = g * wd[2];
                sv[o] = (h * g) * wd[3];
            }
            Bh[kk].u[p] = pk2(hv[0], hv[1]); Bx[kk].u[p] = pk2(xv[0], xv[1]);
            By[kk].u[p] = pk2(yv[0], yv[1]); Bz[kk].u[p] = pk2(zv[0], zv[1]);
            Bs[kk].u[p] = pk2(sv[0], sv[1]);
        }

        // ---- layer 2: per-mt MFMA -> NL -> pack -> write (5-state exchange) ----
#pragma unroll
        for (int mt = 0; mt < 4; ++mt) {
            f4 Ch = {0.f,0.f,0.f,0.f}, Cx = {0.f,0.f,0.f,0.f}, Cy = {0.f,0.f,0.f,0.f},
               Cz = {0.f,0.f,0.f,0.f}, Cs = {0.f,0.f,0.f,0.f};
            MFMA10(A2f)
            const f4 bb = BbK2[4 * mt + q];
            float oh[4], ox[4], oy[4], oz[4], os[4];
#pragma unroll
            for (int r = 0; r < 4; ++r) {
                float h, g; tanh_sech2_t(fmaf(Ch[r], K2L, bb[r]), h, g);
                const float ax = Cx[r], ay = Cy[r], az = Cz[r];
                const float qq  = fmaf(ax, ax, fmaf(ay, ay, az * az));
                const float hg2 = (h * g) * 2.f;
                oh[r] = h; ox[r] = g * ax; oy[r] = g * ay; oz[r] = g * az;
                os[r] = fmaf(g, Cs[r], -(hg2 * qq));
            }
            WR5(mt)
        }

        // ---- B-fragments for layer 3: reload into the SAME registers ----
        RDB(Bh, 0) RDB(Bx, 1) RDB(By, 2) RDB(Bz, 3) RDB(Bs, 4)

        // ---- layer 3: per-mt MFMA -> NL -> dot with W4 ----
        float tot = 0.f;
#pragma unroll
        for (int mt = 0; mt < 4; ++mt) {
            f4 Ch = {0.f,0.f,0.f,0.f}, Cx = {0.f,0.f,0.f,0.f}, Cy = {0.f,0.f,0.f,0.f},
               Cz = {0.f,0.f,0.f,0.f}, Cs = {0.f,0.f,0.f,0.f};
            MFMA10(A3f)
            const f4 bb = BbK3[4 * mt + q], w4 = W4v[4 * mt + q];
#pragma unroll
            for (int r = 0; r < 4; ++r) {
                float h, g; tanh_sech2_t(fmaf(Ch[r], K2L, bb[r]), h, g);
                const float ax = Cx[r], ay = Cy[r], az = Cz[r];
                const float qq  = fmaf(ax, ax, fmaf(ay, ay, az * az));
                const float hg2 = (h * g) * 2.f;
                const float sv  = fmaf(g, Cs[r], -(hg2 * qq));
                tot = fmaf(sv, w4[r], tot);
            }
        }
        tot += __shfl_xor(tot, 16);
        tot += __shfl_xor(tot, 32);
        if (lane < 16) out[(long)b * 16 + sb] = sg * tot;
    }
}

extern "C" void kernel_launch(void* const* d_in, const int* in_sizes, int n_in,
                              void* d_out, int out_size, void* d_ws, size_t ws_size,
                              hipStream_t stream) {
    const float* x_r     = (const float*)d_in[0];
    const float* sigma_r = (const float*)d_in[1];
    const float* W1      = (const float*)d_in[2];
    const float* b1      = (const float*)d_in[3];
    const float* W2      = (const float*)d_in[4];
    const float* b2      = (const float*)d_in[5];
    const float* W3      = (const float*)d_in[6];
    const float* b3      = (const float*)d_in[7];
    const float* W4      = (const float*)d_in[8];
    float* out = (float*)d_out;

    pinn_mfma_kernel<<<NBLOCKS, 256, 0, stream>>>(
        x_r, sigma_r, W1, b1, W2, b2, W3, b3, W4, out);
}

// Round 13
// 82.275 us; speedup vs baseline: 1.5771x; 1.2917x over previous
//
#include <hip/hip_runtime.h>

typedef __fp16 f16;
typedef f16  h8 __attribute__((ext_vector_type(8)));
typedef float f4 __attribute__((ext_vector_type(4)));
typedef unsigned u32t;

#define NBLOCKS 512              // 256 CUs x 2 blocks/CU co-resident at bounds=2
#define WPB 4
#define NWAVES (NBLOCKS * WPB)   // 2048 waves; 16384 batches -> 8 per wave
#define NBAT (262144 / 16)
#define K2L 2.8853900817779268f  // 2*log2(e):  e^{2a} = 2^{K2L*a}

union H8u { h8 v; u32t u[4]; };
union U4h { uint4 u; h8 v; };

__device__ __forceinline__ u32t pk2(float a, float b) {
    return __builtin_bit_cast(u32t, __builtin_amdgcn_cvt_pkrtz(a, b));
}

// h = tanh(a), g = sech^2(a) given t = K2L*a (E = 2^t = e^{2a}); NaN-free at sat.
__device__ __forceinline__ void tanh_sech2_t(float t, float& h, float& g) {
    float E = __builtin_amdgcn_exp2f(t);
    float inv = __builtin_amdgcn_rcpf(E + 1.f);
    float u = inv + inv;
    h = 1.f - u;
    g = u * (2.f - u);
}

// R13 = R11 source verbatim (zero-exchange: L1 emits B2-frags directly; L2->L3
// via pi3 same-lane register repack; A2 in regs, A3 in 8KB LDS) with the
// register CAP raised: __launch_bounds__(256,2) -> ~256 VGPR budget.
// 12-round lesson: every bounds=3 (~170 cap) variant except the R4/R10 shape
// spilled 260-450MB to scratch; liveness here ~190 needs the 256 cap.
// Occupancy 2 blocks/CU is sufficient: traffic is 2.3MB total, all latency is
// trans/MFMA and hidden by intra-wave ILP (5 indep accum chains, 4-wide NL).
__global__ __launch_bounds__(256, 2) void pinn_mfma_kernel(
    const float* __restrict__ x_r, const float* __restrict__ sigma_r,
    const float* __restrict__ W1, const float* __restrict__ b1,
    const float* __restrict__ W2, const float* __restrict__ b2,
    const float* __restrict__ W3, const float* __restrict__ b3,
    const float* __restrict__ W4, float* __restrict__ out)
{
    __shared__ uint4 F3[8][64];             // A3 frags under pi3, 8 KB
    __shared__ f4 Wk[64];                   // (K*w1x, K*w1y, K*w1z, K*b1)
    __shared__ f4 Wd[64];                   // (w1x, w1y, w1z, -2*Q1)
    __shared__ f4 BbK2[16], BbK3[16], W4v[16];

    const int tid = threadIdx.x, lane = tid & 63, wv = tid >> 6;
    const int sb = lane & 15;   // sample slot (B/C col)
    const int q  = lane >> 4;   // lane quarter (C row group / B k-chunk)

    if (tid < 64) {
        float wx = W1[tid], wy = W1[64 + tid], wz = W1[128 + tid];
        f4 a; a[0] = K2L * wx; a[1] = K2L * wy; a[2] = K2L * wz; a[3] = K2L * b1[tid];
        Wk[tid] = a;
        f4 d; d[0] = wx; d[1] = wy; d[2] = wz; d[3] = -2.f * (wx*wx + wy*wy + wz*wz);
        Wd[tid] = d;
        ((float*)BbK2)[tid] = K2L * b2[tid];
        ((float*)BbK3)[tid] = K2L * b3[tid];
        ((float*)W4v)[tid]  = W4[tid];
    }
    // Fill F3 (pi3 rows: 32kk + 16*(p>>1) + 4*qq + 2*(p&1) + o), 2 slots/thread.
#pragma unroll
    for (int i = 0; i < 2; ++i) {
        const int slot = i * 256 + tid;      // 0..511
        const int fg = slot >> 6, ln = slot & 63;
        const int mt = fg >> 1, kk = fg & 1;
        const int qq = ln >> 4, col = 16 * mt + (ln & 15);
        const int rb = (32 * kk + 4 * qq) * 64 + col;
        F3[fg][ln] = make_uint4(
            pk2(W3[rb],        W3[rb + 64]),
            pk2(W3[rb + 128],  W3[rb + 192]),
            pk2(W3[rb + 1024], W3[rb + 1088]),
            pk2(W3[rb + 1152], W3[rb + 1216]));
    }
    __syncthreads();   // the only barrier

    // ---- A2 fragments in registers (identity k-map): A[m][k] = W2[k][m] ----
    h8 A2f[4][2];
#pragma unroll
    for (int mt = 0; mt < 4; ++mt)
#pragma unroll
    for (int kk = 0; kk < 2; ++kk) {
        H8u t2;
#pragma unroll
        for (int p = 0; p < 4; ++p) {
            const int r0 = (32 * kk + 8 * q + 2 * p) * 64 + 16 * mt + sb;
            t2.u[p] = pk2(W2[r0], W2[r0 + 64]);
        }
        A2f[mt][kk] = t2.v;
    }

    const int wave_global = blockIdx.x * WPB + wv;

    // prefetch first batch
    int b = wave_global;
    long sp0 = (long)b * 16 + sb;
    float nx0 = x_r[sp0 * 3], nx1 = x_r[sp0 * 3 + 1], nx2 = x_r[sp0 * 3 + 2],
          nsg = sigma_r[sp0];

#pragma unroll 1
    for (; b < NBAT; b += NWAVES) {
        const float x0 = nx0, x1 = nx1, x2 = nx2, sg = nsg;
        int bn = b + NWAVES;
        if (bn >= NBAT) bn = wave_global;      // dummy re-prefetch on last iter (benign)
        const long sn = (long)bn * 16 + sb;
        nx0 = x_r[sn * 3]; nx1 = x_r[sn * 3 + 1]; nx2 = x_r[sn * 3 + 2];
        nsg = sigma_r[sn];

        // ---- layer 1 straight into B2 fragments (unit = 32kk+8q+2p+o) ----
        H8u Bh[2], Bx[2], By[2], Bz[2], Bs[2];
#pragma unroll
        for (int kk = 0; kk < 2; ++kk)
#pragma unroll
        for (int p = 0; p < 4; ++p) {
            float hv[2], xv[2], yv[2], zv[2], sv[2];
#pragma unroll
            for (int o = 0; o < 2; ++o) {
                const int u = 32 * kk + 8 * q + 2 * p + o;
                const f4 wk = Wk[u], wd = Wd[u];
                const float tt = fmaf(wk[0], x0, fmaf(wk[1], x1, fmaf(wk[2], x2, wk[3])));
                float h, g; tanh_sech2_t(tt, h, g);
                hv[o] = h; xv[o] = g * wd[0]; yv[o] = g * wd[1]; zv[o] = g * wd[2];
                sv[o] = (h * g) * wd[3];
            }
            Bh[kk].u[p] = pk2(hv[0], hv[1]); Bx[kk].u[p] = pk2(xv[0], xv[1]);
            By[kk].u[p] = pk2(yv[0], yv[1]); Bz[kk].u[p] = pk2(zv[0], zv[1]);
            Bs[kk].u[p] = pk2(sv[0], sv[1]);
        }

        // ---- layer 2: per-mt MFMA -> NL -> pi3 same-lane repack into N-frags ----
        H8u Nh[2], Nx[2], Ny[2], Nz[2], Ns[2];
#pragma unroll
        for (int mt = 0; mt < 4; ++mt) {
            f4 Ch = {0.f,0.f,0.f,0.f}, Cx = {0.f,0.f,0.f,0.f}, Cy = {0.f,0.f,0.f,0.f},
               Cz = {0.f,0.f,0.f,0.f}, Cs = {0.f,0.f,0.f,0.f};
#pragma unroll
            for (int kk = 0; kk < 2; ++kk) {
                const h8 A = A2f[mt][kk];
                Ch = __builtin_amdgcn_mfma_f32_16x16x32_f16(A, Bh[kk].v, Ch, 0, 0, 0);
                Cx = __builtin_amdgcn_mfma_f32_16x16x32_f16(A, Bx[kk].v, Cx, 0, 0, 0);
                Cy = __builtin_amdgcn_mfma_f32_16x16x32_f16(A, By[kk].v, Cy, 0, 0, 0);
                Cz = __builtin_amdgcn_mfma_f32_16x16x32_f16(A, Bz[kk].v, Cz, 0, 0, 0);
                Cs = __builtin_amdgcn_mfma_f32_16x16x32_f16(A, Bs[kk].v, Cs, 0, 0, 0);
            }
            const f4 bb = BbK2[4 * mt + q];
            float oh[4], ox[4], oy[4], oz[4], os[4];
#pragma unroll
            for (int r = 0; r < 4; ++r) {
                float h, g; tanh_sech2_t(fmaf(Ch[r], K2L, bb[r]), h, g);
                const float ax = Cx[r], ay = Cy[r], az = Cz[r];
                const float qq  = fmaf(ax, ax, fmaf(ay, ay, az * az));
                const float hg2 = (h * g) * 2.f;
                oh[r] = h; ox[r] = g * ax; oy[r] = g * ay; oz[r] = g * az;
                os[r] = fmaf(g, Cs[r], -(hg2 * qq));
            }
            const int ko = mt >> 1, po = 2 * (mt & 1);
            Nh[ko].u[po] = pk2(oh[0], oh[1]); Nh[ko].u[po + 1] = pk2(oh[2], oh[3]);
            Nx[ko].u[po] = pk2(ox[0], ox[1]); Nx[ko].u[po + 1] = pk2(ox[2], ox[3]);
            Ny[ko].u[po] = pk2(oy[0], oy[1]); Ny[ko].u[po + 1] = pk2(oy[2], oy[3]);
            Nz[ko].u[po] = pk2(oz[0], oz[1]); Nz[ko].u[po + 1] = pk2(oz[2], oz[3]);
            Ns[ko].u[po] = pk2(os[0], os[1]); Ns[ko].u[po + 1] = pk2(os[2], os[3]);
        }

        // ---- layer 3: A3 frags streamed from LDS per-mt -> NL -> W4 dot ----
        float tot = 0.f;
#pragma unroll
        for (int mt = 0; mt < 4; ++mt) {
            f4 Ch = {0.f,0.f,0.f,0.f}, Cx = {0.f,0.f,0.f,0.f}, Cy = {0.f,0.f,0.f,0.f},
               Cz = {0.f,0.f,0.f,0.f}, Cs = {0.f,0.f,0.f,0.f};
#pragma unroll
            for (int kk = 0; kk < 2; ++kk) {
                U4h au; au.u = F3[2 * mt + kk][lane];
                const h8 A = au.v;
                Ch = __builtin_amdgcn_mfma_f32_16x16x32_f16(A, Nh[kk].v, Ch, 0, 0, 0);
                Cx = __builtin_amdgcn_mfma_f32_16x16x32_f16(A, Nx[kk].v, Cx, 0, 0, 0);
                Cy = __builtin_amdgcn_mfma_f32_16x16x32_f16(A, Ny[kk].v, Cy, 0, 0, 0);
                Cz = __builtin_amdgcn_mfma_f32_16x16x32_f16(A, Nz[kk].v, Cz, 0, 0, 0);
                Cs = __builtin_amdgcn_mfma_f32_16x16x32_f16(A, Ns[kk].v, Cs, 0, 0, 0);
            }
            const f4 bb = BbK3[4 * mt + q], w4 = W4v[4 * mt + q];
#pragma unroll
            for (int r = 0; r < 4; ++r) {
                float h, g; tanh_sech2_t(fmaf(Ch[r], K2L, bb[r]), h, g);
                const float ax = Cx[r], ay = Cy[r], az = Cz[r];
                const float qq  = fmaf(ax, ax, fmaf(ay, ay, az * az));
                const float hg2 = (h * g) * 2.f;
                const float sv  = fmaf(g, Cs[r], -(hg2 * qq));
                tot = fmaf(sv, w4[r], tot);
            }
        }
        tot += __shfl_xor(tot, 16);
        tot += __shfl_xor(tot, 32);
        if (lane < 16) out[(long)b * 16 + sb] = sg * tot;
    }
}

extern "C" void kernel_launch(void* const* d_in, const int* in_sizes, int n_in,
                              void* d_out, int out_size, void* d_ws, size_t ws_size,
                              hipStream_t stream) {
    const float* x_r     = (const float*)d_in[0];
    const float* sigma_r = (const float*)d_in[1];
    const float* W1      = (const float*)d_in[2];
    const float* b1      = (const float*)d_in[3];
    const float* W2      = (const float*)d_in[4];
    const float* b2      = (const float*)d_in[5];
    const float* W3      = (const float*)d_in[6];
    const float* b3      = (const float*)d_in[7];
    const float* W4      = (const float*)d_in[8];
    float* out = (float*)d_out;

    pinn_mfma_kernel<<<NBLOCKS, 256, 0, stream>>>(
        x_r, sigma_r, W1, b1, W2, b2, W3, b3, W4, out);
}

// Round 14
// 43.905 us; speedup vs baseline: 2.9555x; 1.8739x over previous
//
#include <hip/hip_runtime.h>

typedef __fp16 f16;
typedef f16  h8 __attribute__((ext_vector_type(8)));
typedef float f4 __attribute__((ext_vector_type(4)));
typedef unsigned u32t;

#define NBLOCKS 768              // 256 CUs x 3 blocks/CU co-resident
#define WPB 4
#define NWAVES (NBLOCKS * WPB)   // 3072
#define NBAT (262144 / 16)       // 16384 batches of 16 samples
#define XSTR 36                  // u32 per sample row (even, 16B-aligned rows)
#define XST  (16 * XSTR)         // u32 per state
#define XWV  (5 * XST + 8)       // per-wave region, +32B stagger between waves
#define K2L 2.8853900817779268f  // 2*log2(e):  e^{2a} = 2^{K2L*a}

union H8u { h8 v; u32t u[4]; };
union U4h { uint4 u; h8 v; };

__device__ __forceinline__ u32t pk2(float a, float b) {
    return __builtin_bit_cast(u32t, __builtin_amdgcn_cvt_pkrtz(a, b));
}

// h = tanh(a), g = sech^2(a) given t = K2L*a (E = 2^t = e^{2a}); NaN-free at sat.
__device__ __forceinline__ void tanh_sech2_t(float t, float& h, float& g) {
    float E = __builtin_amdgcn_exp2f(t);
    float inv = __builtin_amdgcn_rcpf(E + 1.f);
    float u = inv + inv;
    h = 1.f - u;
    g = u * (2.f - u);
}

// R14 = R10 (the ONLY clean high-perf shape: FETCH 2.26MB, 42.6us; every
// structural deviation in R5-R9/R11-R13 spilled 170-450MB scratch) with one
// scheduling change and one free pad:
//  (1) loop ROTATION: L1 of batch b+1 is computed between this batch's L3
//      RDB and the L3 MFMA/NL region (same basic block, branchless dummy-wrap
//      on last iter) so its independent VALU/trans ops fill the MFMA-wait and
//      trans-chain stall gaps that held VALUBusy at 62%. In-order DS makes the
//      slot overwrite safe (L3 RDBs issue before L1(b+1) WR5s).
//  (2) +32B per-wave exchange stagger (bank-footprint decorrelation, free).
// Register liveness is R10-identical: L1 temps are transient per-mt.
__global__ __launch_bounds__(256, 3) void pinn_mfma_kernel(
    const float* __restrict__ x_r, const float* __restrict__ sigma_r,
    const float* __restrict__ W1, const float* __restrict__ b1,
    const float* __restrict__ W2, const float* __restrict__ b2,
    const float* __restrict__ W3, const float* __restrict__ b3,
    const float* __restrict__ W4, float* __restrict__ out)
{
    __shared__ f4 Wg[64];                   // (w1x, w1y, w1z, -2*Q1)
    __shared__ f4 Wb4[16], BbK2[16], BbK3[16], W4v[16];
    __shared__ u32t xch[WPB][XWV];          // f16-pair exchange, staggered

    const int tid = threadIdx.x, lane = tid & 63, wv = tid >> 6;
    const int sb = lane & 15;   // sample slot (B/C col)
    const int q  = lane >> 4;   // lane quarter (C row group / B k-chunk)

    if (tid < 64) {
        float wx = W1[tid], wy = W1[64 + tid], wz = W1[128 + tid];
        f4 w; w[0] = wx; w[1] = wy; w[2] = wz;
        w[3] = -2.f * (wx * wx + wy * wy + wz * wz);
        Wg[tid] = w;
        ((float*)Wb4)[tid]  = b1[tid];
        ((float*)BbK2)[tid] = K2L * b2[tid];
        ((float*)BbK3)[tid] = K2L * b3[tid];
        ((float*)W4v)[tid]  = W4[tid];
    }
    __syncthreads();   // the only barrier

    // ---- A-fragments (validated mapping): A[m][k] = W[32kk+8q+e][16mt+sb] ----
    h8 A2f[4][2], A3f[4][2];
#pragma unroll
    for (int mt = 0; mt < 4; ++mt)
#pragma unroll
    for (int kk = 0; kk < 2; ++kk) {
        H8u t2, t3;
#pragma unroll
        for (int p = 0; p < 4; ++p) {
            const int r0 = (32 * kk + 8 * q + 2 * p) * 64 + 16 * mt + sb;
            t2.u[p] = pk2(W2[r0], W2[r0 + 64]);
            t3.u[p] = pk2(W3[r0], W3[r0 + 64]);
        }
        A2f[mt][kk] = t2.v; A3f[mt][kk] = t3.v;
    }

    u32t* xb = xch[wv];
    const int wbase = sb * XSTR + 2 * q;   // + 8*mt + st*XST   (b64 writes)
    const int rbase = sb * XSTR + 4 * q;   // + 16*kk + st*XST  (b128 reads)

    const int wave_global = blockIdx.x * WPB + wv;

#define WR5(mt) { const int wo = wbase + 8 * (mt);                                         \
    *(uint2*)&xb[0 * XST + wo] = make_uint2(pk2(oh[0], oh[1]), pk2(oh[2], oh[3]));         \
    *(uint2*)&xb[1 * XST + wo] = make_uint2(pk2(ox[0], ox[1]), pk2(ox[2], ox[3]));         \
    *(uint2*)&xb[2 * XST + wo] = make_uint2(pk2(oy[0], oy[1]), pk2(oy[2], oy[3]));         \
    *(uint2*)&xb[3 * XST + wo] = make_uint2(pk2(oz[0], oz[1]), pk2(oz[2], oz[3]));         \
    *(uint2*)&xb[4 * XST + wo] = make_uint2(pk2(os[0], os[1]), pk2(os[2], os[3])); }

#define RDB(Bf, st) { U4h u0, u1;                                                          \
    u0.u = *(const uint4*)&xb[(st) * XST + rbase];                                         \
    u1.u = *(const uint4*)&xb[(st) * XST + rbase + 16];                                    \
    Bf[0] = u0.v; Bf[1] = u1.v; }

#define MFMA10(Af) _Pragma("unroll")                                                       \
    for (int kk = 0; kk < 2; ++kk) {                                                       \
        Ch = __builtin_amdgcn_mfma_f32_16x16x32_f16(Af[mt][kk], Bh[kk], Ch, 0, 0, 0);      \
        Cx = __builtin_amdgcn_mfma_f32_16x16x32_f16(Af[mt][kk], Bx[kk], Cx, 0, 0, 0);      \
        Cy = __builtin_amdgcn_mfma_f32_16x16x32_f16(Af[mt][kk], By[kk], Cy, 0, 0, 0);      \
        Cz = __builtin_amdgcn_mfma_f32_16x16x32_f16(Af[mt][kk], Bz[kk], Cz, 0, 0, 0);      \
        Cs = __builtin_amdgcn_mfma_f32_16x16x32_f16(Af[mt][kk], Bs[kk], Cs, 0, 0, 0);      \
    }

// layer 1 in C layout for inputs (XX0,XX1,XX2): NL + pack + WR5, temps per-mt
#define L1BLOCK(XX0, XX1, XX2)                                                             \
    _Pragma("unroll")                                                                      \
    for (int mt = 0; mt < 4; ++mt) {                                                       \
        const f4 bb = Wb4[4 * mt + q];                                                     \
        float oh[4], ox[4], oy[4], oz[4], os[4];                                           \
        _Pragma("unroll")                                                                  \
        for (int r = 0; r < 4; ++r) {                                                      \
            const f4 w = Wg[16 * mt + 4 * q + r];                                          \
            const float a = fmaf(w[0], XX0, fmaf(w[1], XX1, fmaf(w[2], XX2, bb[r])));      \
            float h, g; tanh_sech2_t(K2L * a, h, g);                                       \
            oh[r] = h; ox[r] = g * w[0]; oy[r] = g * w[1]; oz[r] = g * w[2];               \
            os[r] = (h * g) * w[3];                                                        \
        }                                                                                  \
        WR5(mt)                                                                            \
    }

    // ---- prologue: batch 0 inputs + its L1 into the exchange ----
    int b = wave_global;
    long sp0 = (long)b * 16 + sb;
    float x0 = x_r[sp0 * 3], x1 = x_r[sp0 * 3 + 1], x2 = x_r[sp0 * 3 + 2],
          sg = sigma_r[sp0];
    L1BLOCK(x0, x1, x2)

#pragma unroll 1
    for (; b < NBAT; b += NWAVES) {
        int bn = b + NWAVES;
        if (bn >= NBAT) bn = wave_global;      // dummy wrap on last iter (benign)
        const long sn = (long)bn * 16 + sb;
        const float nx0 = x_r[sn * 3], nx1 = x_r[sn * 3 + 1], nx2 = x_r[sn * 3 + 2];
        const float nsg = sigma_r[sn];

        // ---- B-fragments for layer 2 (in-order DS: reads after L1 writes) ----
        h8 Bh[2], Bx[2], By[2], Bz[2], Bs[2];
        RDB(Bh, 0) RDB(Bx, 1) RDB(By, 2) RDB(Bz, 3) RDB(Bs, 4)

        // ---- layer 2: per-mt MFMA -> NL -> pack -> write ----
#pragma unroll
        for (int mt = 0; mt < 4; ++mt) {
            f4 Ch = {0.f,0.f,0.f,0.f}, Cx = {0.f,0.f,0.f,0.f}, Cy = {0.f,0.f,0.f,0.f},
               Cz = {0.f,0.f,0.f,0.f}, Cs = {0.f,0.f,0.f,0.f};
            MFMA10(A2f)
            const f4 bb = BbK2[4 * mt + q];
            float oh[4], ox[4], oy[4], oz[4], os[4];
#pragma unroll
            for (int r = 0; r < 4; ++r) {
                float h, g; tanh_sech2_t(fmaf(Ch[r], K2L, bb[r]), h, g);
                const float ax = Cx[r], ay = Cy[r], az = Cz[r];
                const float qq  = fmaf(ax, ax, fmaf(ay, ay, az * az));
                const float hg2 = (h * g) * 2.f;
                oh[r] = h; ox[r] = g * ax; oy[r] = g * ay; oz[r] = g * az;
                os[r] = fmaf(g, Cs[r], -(hg2 * qq));
            }
            WR5(mt)
        }

        // ---- B-fragments for layer 3 ----
        RDB(Bh, 0) RDB(Bx, 1) RDB(By, 2) RDB(Bz, 3) RDB(Bs, 4)

        // ---- L1 of NEXT batch here: independent VALU/trans ops for the
        //      scheduler to interleave into L3's MFMA-wait gaps. Its WR5s are
        //      issued after the RDBs above (in-order DS -> safe overwrite). ----
        L1BLOCK(nx0, nx1, nx2)

        // ---- layer 3: per-mt MFMA -> NL -> dot with W4 ----
        float tot = 0.f;
#pragma unroll
        for (int mt = 0; mt < 4; ++mt) {
            f4 Ch = {0.f,0.f,0.f,0.f}, Cx = {0.f,0.f,0.f,0.f}, Cy = {0.f,0.f,0.f,0.f},
               Cz = {0.f,0.f,0.f,0.f}, Cs = {0.f,0.f,0.f,0.f};
            MFMA10(A3f)
            const f4 bb = BbK3[4 * mt + q], w4 = W4v[4 * mt + q];
#pragma unroll
            for (int r = 0; r < 4; ++r) {
                float h, g; tanh_sech2_t(fmaf(Ch[r], K2L, bb[r]), h, g);
                const float ax = Cx[r], ay = Cy[r], az = Cz[r];
                const float qq  = fmaf(ax, ax, fmaf(ay, ay, az * az));
                const float hg2 = (h * g) * 2.f;
                const float sv  = fmaf(g, Cs[r], -(hg2 * qq));
                tot = fmaf(sv, w4[r], tot);
            }
        }
        tot += __shfl_xor(tot, 16);
        tot += __shfl_xor(tot, 32);
        if (lane < 16) out[(long)b * 16 + sb] = sg * tot;

        x0 = nx0; x1 = nx1; x2 = nx2; sg = nsg;   // carry next batch's inputs
    }
}

extern "C" void kernel_launch(void* const* d_in, const int* in_sizes, int n_in,
                              void* d_out, int out_size, void* d_ws, size_t ws_size,
                              hipStream_t stream) {
    const float* x_r     = (const float*)d_in[0];
    const float* sigma_r = (const float*)d_in[1];
    const float* W1      = (const float*)d_in[2];
    const float* b1      = (const float*)d_in[3];
    const float* W2      = (const float*)d_in[4];
    const float* b2      = (const float*)d_in[5];
    const float* W3      = (const float*)d_in[6];
    const float* b3      = (const float*)d_in[7];
    const float* W4      = (const float*)d_in[8];
    float* out = (float*)d_out;

    pinn_mfma_kernel<<<NBLOCKS, 256, 0, stream>>>(
        x_r, sigma_r, W1, b1, W2, b2, W3, b3, W4, out);
}

// Round 15
// 42.311 us; speedup vs baseline: 3.0668x; 1.0377x over previous
//
#include <hip/hip_runtime.h>

typedef __fp16 f16;
typedef f16  h8 __attribute__((ext_vector_type(8)));
typedef float f4 __attribute__((ext_vector_type(4)));
typedef unsigned u32t;

#define NBLOCKS 768              // 256 CUs x 3 blocks/CU co-resident (LDS-bound)
#define WPB 4
#define NWAVES (NBLOCKS * WPB)   // 3072
#define NBAT (262144 / 16)       // 16384 batches of 16 samples
#define XSTR 36                  // u32 per sample row (even, 16B-aligned rows)
#define XST  (16 * XSTR)         // u32 per state
#define K2L 2.8853900817779268f  // 2*log2(e):  e^{2a} = 2^{K2L*a}

union H8u { h8 v; u32t u[4]; };
union U4h { uint4 u; h8 v; };

__device__ __forceinline__ u32t pk2(float a, float b) {
    return __builtin_bit_cast(u32t, __builtin_amdgcn_cvt_pkrtz(a, b));
}

// h = tanh(a), g = sech^2(a) given t = K2L*a (E = 2^t = e^{2a}); NaN-free at sat.
__device__ __forceinline__ void tanh_sech2_t(float t, float& h, float& g) {
    float E = __builtin_amdgcn_exp2f(t);
    float inv = __builtin_amdgcn_rcpf(E + 1.f);
    float u = inv + inv;
    h = 1.f - u;
    g = u * (2.f - u);
}

// R15 = R10 (the ONLY clean high-perf shape: FETCH 2.26MB, 42.6us) + two pure
// expression rewrites, no structural change:
//  (1) L1 tables pre-scaled: Wk = K2L*(W1|b1) feeds exp2 arg directly (kills
//      the per-unit K2L*a mul); Wd = (W1 | -2*Q1) for derivatives.
//  (2) 3-op 2nd-order update: os = g * fmaf(-(h+h), qq, Cs)  [neg folds into
//      the fmaf modifier] replacing the 4-op hg2 form, in L2 and L3.
// HISTORY (14 rounds): every structural deviation -- pi3 zero-exchange
// (R5-R8,R11-R13), held-reg slot reuse (R9), direct-L1+gridstride (R12),
// loop rotation (R14) -- either spilled 170-450MB scratch or was neutral.
// Unified reg demand ~156/wave: bounds=3 fits, bounds=4/cap-128 spills.
// Occupancy is LDS-locked at 3 blocks/CU (exchange 46KB). DO NOT restructure.
__global__ __launch_bounds__(256, 3) void pinn_mfma_kernel(
    const float* __restrict__ x_r, const float* __restrict__ sigma_r,
    const float* __restrict__ W1, const float* __restrict__ b1,
    const float* __restrict__ W2, const float* __restrict__ b2,
    const float* __restrict__ W3, const float* __restrict__ b3,
    const float* __restrict__ W4, float* __restrict__ out)
{
    __shared__ f4 Wk[64];                   // (K*w1x, K*w1y, K*w1z, K*b1)
    __shared__ f4 Wd[64];                   // (w1x, w1y, w1z, -2*Q1)
    __shared__ f4 BbK2[16], BbK3[16], W4v[16];
    __shared__ u32t xch[WPB][5 * XST];      // f16-pair exchange, 46 KB

    const int tid = threadIdx.x, lane = tid & 63, wv = tid >> 6;
    const int sb = lane & 15;   // sample slot (B/C col)
    const int q  = lane >> 4;   // lane quarter (C row group / B k-chunk)

    if (tid < 64) {
        float wx = W1[tid], wy = W1[64 + tid], wz = W1[128 + tid];
        f4 a; a[0] = K2L * wx; a[1] = K2L * wy; a[2] = K2L * wz; a[3] = K2L * b1[tid];
        Wk[tid] = a;
        f4 d; d[0] = wx; d[1] = wy; d[2] = wz; d[3] = -2.f * (wx*wx + wy*wy + wz*wz);
        Wd[tid] = d;
        ((float*)BbK2)[tid] = K2L * b2[tid];
        ((float*)BbK3)[tid] = K2L * b3[tid];
        ((float*)W4v)[tid]  = W4[tid];
    }
    __syncthreads();   // the only barrier

    // ---- A-fragments (validated mapping): A[m][k] = W[32kk+8q+e][16mt+sb] ----
    h8 A2f[4][2], A3f[4][2];
#pragma unroll
    for (int mt = 0; mt < 4; ++mt)
#pragma unroll
    for (int kk = 0; kk < 2; ++kk) {
        H8u t2, t3;
#pragma unroll
        for (int p = 0; p < 4; ++p) {
            const int r0 = (32 * kk + 8 * q + 2 * p) * 64 + 16 * mt + sb;
            t2.u[p] = pk2(W2[r0], W2[r0 + 64]);
            t3.u[p] = pk2(W3[r0], W3[r0 + 64]);
        }
        A2f[mt][kk] = t2.v; A3f[mt][kk] = t3.v;
    }

    u32t* xb = xch[wv];
    const int wbase = sb * XSTR + 2 * q;   // + 8*mt + st*XST   (b64 writes)
    const int rbase = sb * XSTR + 4 * q;   // + 16*kk + st*XST  (b128 reads)

    const int wave_global = blockIdx.x * WPB + wv;

#define WR5(mt) { const int wo = wbase + 8 * (mt);                                         \
    *(uint2*)&xb[0 * XST + wo] = make_uint2(pk2(oh[0], oh[1]), pk2(oh[2], oh[3]));         \
    *(uint2*)&xb[1 * XST + wo] = make_uint2(pk2(ox[0], ox[1]), pk2(ox[2], ox[3]));         \
    *(uint2*)&xb[2 * XST + wo] = make_uint2(pk2(oy[0], oy[1]), pk2(oy[2], oy[3]));         \
    *(uint2*)&xb[3 * XST + wo] = make_uint2(pk2(oz[0], oz[1]), pk2(oz[2], oz[3]));         \
    *(uint2*)&xb[4 * XST + wo] = make_uint2(pk2(os[0], os[1]), pk2(os[2], os[3])); }

#define RDB(Bf, st) { U4h u0, u1;                                                          \
    u0.u = *(const uint4*)&xb[(st) * XST + rbase];                                         \
    u1.u = *(const uint4*)&xb[(st) * XST + rbase + 16];                                    \
    Bf[0] = u0.v; Bf[1] = u1.v; }

#define MFMA10(Af) _Pragma("unroll")                                                       \
    for (int kk = 0; kk < 2; ++kk) {                                                       \
        Ch = __builtin_amdgcn_mfma_f32_16x16x32_f16(Af[mt][kk], Bh[kk], Ch, 0, 0, 0);      \
        Cx = __builtin_amdgcn_mfma_f32_16x16x32_f16(Af[mt][kk], Bx[kk], Cx, 0, 0, 0);      \
        Cy = __builtin_amdgcn_mfma_f32_16x16x32_f16(Af[mt][kk], By[kk], Cy, 0, 0, 0);      \
        Cz = __builtin_amdgcn_mfma_f32_16x16x32_f16(Af[mt][kk], Bz[kk], Cz, 0, 0, 0);      \
        Cs = __builtin_amdgcn_mfma_f32_16x16x32_f16(Af[mt][kk], Bs[kk], Cs, 0, 0, 0);      \
    }

    // prefetch first batch
    int b = wave_global;
    long sp0 = (long)b * 16 + sb;
    float nx0 = x_r[sp0 * 3], nx1 = x_r[sp0 * 3 + 1], nx2 = x_r[sp0 * 3 + 2],
          nsg = sigma_r[sp0];

#pragma unroll 1
    for (; b < NBAT; b += NWAVES) {
        const float x0 = nx0, x1 = nx1, x2 = nx2, sg = nsg;
        int bn = b + NWAVES;
        if (bn >= NBAT) bn = wave_global;      // dummy re-prefetch on last iter (benign)
        const long sn = (long)bn * 16 + sb;
        nx0 = x_r[sn * 3]; nx1 = x_r[sn * 3 + 1]; nx2 = x_r[sn * 3 + 2];
        nsg = sigma_r[sn];

        // ---- layer 1 in C layout (t = Wk.(x,1) directly), pack, write ----
#pragma unroll
        for (int mt = 0; mt < 4; ++mt) {
            float oh[4], ox[4], oy[4], oz[4], os[4];
#pragma unroll
            for (int r = 0; r < 4; ++r) {
                const int u = 16 * mt + 4 * q + r;
                const f4 wk = Wk[u], wd = Wd[u];
                const float tt = fmaf(wk[0], x0, fmaf(wk[1], x1, fmaf(wk[2], x2, wk[3])));
                float h, g; tanh_sech2_t(tt, h, g);
                oh[r] = h; ox[r] = g * wd[0]; oy[r] = g * wd[1]; oz[r] = g * wd[2];
                os[r] = (h * g) * wd[3];              // -2*h*g*Q1
            }
            WR5(mt)
        }

        // ---- B-fragments for layer 2 (in-order DS: reads after writes) ----
        h8 Bh[2], Bx[2], By[2], Bz[2], Bs[2];
        RDB(Bh, 0) RDB(Bx, 1) RDB(By, 2) RDB(Bz, 3) RDB(Bs, 4)

        // ---- layer 2: per-mt MFMA -> NL -> pack -> write ----
#pragma unroll
        for (int mt = 0; mt < 4; ++mt) {
            f4 Ch = {0.f,0.f,0.f,0.f}, Cx = {0.f,0.f,0.f,0.f}, Cy = {0.f,0.f,0.f,0.f},
               Cz = {0.f,0.f,0.f,0.f}, Cs = {0.f,0.f,0.f,0.f};
            MFMA10(A2f)
            const f4 bb = BbK2[4 * mt + q];
            float oh[4], ox[4], oy[4], oz[4], os[4];
#pragma unroll
            for (int r = 0; r < 4; ++r) {
                float h, g; tanh_sech2_t(fmaf(Ch[r], K2L, bb[r]), h, g);
                const float ax = Cx[r], ay = Cy[r], az = Cz[r];
                const float qq = fmaf(ax, ax, fmaf(ay, ay, az * az));
                const float h2 = h + h;
                oh[r] = h; ox[r] = g * ax; oy[r] = g * ay; oz[r] = g * az;
                os[r] = g * fmaf(-h2, qq, Cs[r]);     // 3-op form, neg in modifier
            }
            WR5(mt)
        }

        // ---- B-fragments for layer 3 ----
        RDB(Bh, 0) RDB(Bx, 1) RDB(By, 2) RDB(Bz, 3) RDB(Bs, 4)

        // ---- layer 3: per-mt MFMA -> NL -> dot with W4 ----
        float tot = 0.f;
#pragma unroll
        for (int mt = 0; mt < 4; ++mt) {
            f4 Ch = {0.f,0.f,0.f,0.f}, Cx = {0.f,0.f,0.f,0.f}, Cy = {0.f,0.f,0.f,0.f},
               Cz = {0.f,0.f,0.f,0.f}, Cs = {0.f,0.f,0.f,0.f};
            MFMA10(A3f)
            const f4 bb = BbK3[4 * mt + q], w4 = W4v[4 * mt + q];
#pragma unroll
            for (int r = 0; r < 4; ++r) {
                float h, g; tanh_sech2_t(fmaf(Ch[r], K2L, bb[r]), h, g);
                const float ax = Cx[r], ay = Cy[r], az = Cz[r];
                const float qq = fmaf(ax, ax, fmaf(ay, ay, az * az));
                const float h2 = h + h;
                const float sv = g * fmaf(-h2, qq, Cs[r]);
                tot = fmaf(sv, w4[r], tot);
            }
        }
        tot += __shfl_xor(tot, 16);
        tot += __shfl_xor(tot, 32);
        if (lane < 16) out[(long)b * 16 + sb] = sg * tot;
    }
}

extern "C" void kernel_launch(void* const* d_in, const int* in_sizes, int n_in,
                              void* d_out, int out_size, void* d_ws, size_t ws_size,
                              hipStream_t stream) {
    const float* x_r     = (const float*)d_in[0];
    const float* sigma_r = (const float*)d_in[1];
    const float* W1      = (const float*)d_in[2];
    const float* b1      = (const float*)d_in[3];
    const float* W2      = (const float*)d_in[4];
    const float* b2      = (const float*)d_in[5];
    const float* W3      = (const float*)d_in[6];
    const float* b3      = (const float*)d_in[7];
    const float* W4      = (const float*)d_in[8];
    float* out = (float*)d_out;

    pinn_mfma_kernel<<<NBLOCKS, 256, 0, stream>>>(
        x_r, sigma_r, W1, b1, W2, b2, W3, b3, W4, out);
}